// Round 8
// baseline (405.636 us; speedup 1.0000x reference)
//
#include <hip/hip_runtime.h>
#include <stdint.h>
#include <stddef.h>

// ---------------------------------------------------------------------------
// SimpleRNN (gated linear attention) — chunked parallel formulation.
//   q = hs@Wq^T+bq ; k = sig(hs@Wk^T+bk) ; g = sig(hs@Wg^T+bg) ; v = hs@Wv^T+bv
//   S_t = diag(g_t) S_{t-1} + k_t v_t^T ; out_t = q_t S_t ; y = out@Wo^T+bo
// Chunked (C=64): la = within-chunk cumsum(log g) [fused in k_transform],
//   q~ = q*exp(la), k~ = k*exp(-la), kbar = k*exp(laC-la)
//   out = tril(q~ k~^T) V  +  q~ @ S_prev
//   U_c = kbar^T V ;  S_c = exp(laC) (.) S_{c-1} + U_c   (elementwise scan)
//
// R8: LDS is the binding resource (R7: 48KB 3-buf -> 3 blocks/CU).
// gemm_core -> 2-buffer (32KB) = 5 blocks/CU; K-split grids supply the
// blocks (projA 2048, outA 1024, ugemm 2048, inter2 512 via BN=64).
// ---------------------------------------------------------------------------

#define DEVI __device__ __forceinline__

typedef __bf16 bf16;
typedef __bf16 bf16x8 __attribute__((ext_vector_type(8)));
typedef __bf16 bf16x4 __attribute__((ext_vector_type(4)));
typedef float  f32x4  __attribute__((ext_vector_type(4)));

static constexpr int T_  = 4096;
static constexpr int H_  = 2048;
static constexpr int KD  = 1024;
static constexpr int VD  = 1024;
static constexpr int OD  = 2048;
static constexpr int CH  = 64;                 // chunk length
static constexpr int NCHUNK = T_ / CH;         // 64
static constexpr int NGROUP = 2;               // chunk groups (ws economy)
static constexpr int CPG    = NCHUNK / NGROUP; // 32

DEVI bf16 tobf(float f) {
  union { float f; uint32_t u; } x; x.f = f;
  uint32_t r = (x.u + 0x7FFFu + ((x.u >> 16) & 1u)) >> 16;  // RNE
  union { uint16_t s; bf16 b; } y; y.s = (uint16_t)r;
  return y.b;
}

DEVI f32x4 fzero() { f32x4 z = {0.f, 0.f, 0.f, 0.f}; return z; }

// async global->LDS, 16B per lane (lane-linear LDS destination).
DEVI void gld16(const bf16* g, bf16* l) {
  auto* g1 = reinterpret_cast<__attribute__((address_space(1))) uint32_t*>(
      (uintptr_t)g);
  auto* l3 = reinterpret_cast<__attribute__((address_space(3))) uint32_t*>(
      (uintptr_t)l);
  __builtin_amdgcn_global_load_lds(g1, l3, 16, 0, 0);
}

// C[m0..+BM, n0..+BN] += A[M,K] * B[N,K]^T, both row-major K-contiguous.
// 4 waves in 2x2; BK=32; 2-buffer (32KB at 128x128 -> 5 blocks/CU), one
// __syncthreads per K-step (drain hidden by TLP at 5 blocks/CU).
template<int BM, int BN>
DEVI void gemm_core(const bf16* A, int lda, int m0,
                    const bf16* B, int ldb, int n0,
                    int K, f32x4* acc, bf16* sA, bf16* sB, int tid)
{
  constexpr int MR = BM / 32;
  constexpr int NR = BN / 32;
  constexpr int ASZ = BM * 32;
  constexpr int BSZ = BN * 32;
  const int lane = tid & 63;
  const int wr = (tid >> 6) >> 1;
  const int wc = (tid >> 6) & 1;
  const int srow = tid >> 2;
  const int skof = (tid & 3) * 8;
  const bf16* aB = A + (size_t)(m0 + srow) * lda + skof;
  const bf16* bB = B + (size_t)(n0 + srow) * ldb + skof;

  auto stage = [&](int t, int buf) {
    const int k0 = t * 32;
#pragma unroll
    for (int r = 0; r < BM / 64; ++r)
      gld16(aB + (size_t)r * 64 * lda + k0, sA + buf * ASZ + r * 2048 + tid * 8);
#pragma unroll
    for (int r = 0; r < BN / 64; ++r)
      gld16(bB + (size_t)r * 64 * ldb + k0, sB + buf * BSZ + r * 2048 + tid * 8);
  };

  const int nt = K / 32;
  stage(0, 0);
  for (int t = 0; t < nt; ++t) {
    __syncthreads();                    // drains vmcnt: tile t resident
    if (t + 1 < nt) stage(t + 1, (t + 1) & 1);
    const bf16* pA = sA + (t & 1) * ASZ;
    const bf16* pB = sB + (t & 1) * BSZ;
    bf16x8 af[MR], bfr[NR];
#pragma unroll
    for (int m = 0; m < MR; ++m)
      af[m] = *(const bf16x8*)(pA + (wr * (MR * 16) + m * 16 + (lane & 15)) * 32
                               + (lane >> 4) * 8);
#pragma unroll
    for (int n = 0; n < NR; ++n)
      bfr[n] = *(const bf16x8*)(pB + (wc * (NR * 16) + n * 16 + (lane & 15)) * 32
                                + (lane >> 4) * 8);
#pragma unroll
    for (int m = 0; m < MR; ++m)
#pragma unroll
      for (int n = 0; n < NR; ++n)
        acc[m * NR + n] = __builtin_amdgcn_mfma_f32_16x16x32_bf16(
            af[m], bfr[n], acc[m * NR + n], 0, 0, 0);
  }
}

// ---------------------------------------------------------------------------
static constexpr size_t CVT_HS = (size_t)T_ * H_;
static constexpr size_t CVT_W  = (size_t)KD * H_;
static constexpr size_t CVT_WO = (size_t)OD * VD;
static constexpr size_t CVT_TOT = CVT_HS + 4 * CVT_W + CVT_WO;

__global__ __launch_bounds__(256) void k_cvt6(
    const float* __restrict__ hs, const float* __restrict__ Wq,
    const float* __restrict__ Wk, const float* __restrict__ Wg,
    const float* __restrict__ Wv, const float* __restrict__ Wo,
    bf16* __restrict__ hsb, bf16* __restrict__ Wqb,
    bf16* __restrict__ Wkb, bf16* __restrict__ Wgb,
    bf16* __restrict__ Wvb, bf16* __restrict__ Wob)
{
  size_t i = ((size_t)blockIdx.x * 256 + threadIdx.x) * 4;
  if (i >= CVT_TOT) return;
  const float* s; bf16* d; size_t off;
  if (i < CVT_HS)                { s = hs; d = hsb; off = i; }
  else if (i < CVT_HS + CVT_W)   { s = Wq; d = Wqb; off = i - CVT_HS; }
  else if (i < CVT_HS + 2*CVT_W) { s = Wk; d = Wkb; off = i - CVT_HS - CVT_W; }
  else if (i < CVT_HS + 3*CVT_W) { s = Wg; d = Wgb; off = i - CVT_HS - 2*CVT_W; }
  else if (i < CVT_HS + 4*CVT_W) { s = Wv; d = Wvb; off = i - CVT_HS - 3*CVT_W; }
  else                           { s = Wo; d = Wob; off = i - CVT_HS - 4*CVT_W; }
  float4 v = *(const float4*)(s + off);
  bf16x4 o; o[0] = tobf(v.x); o[1] = tobf(v.y); o[2] = tobf(v.z); o[3] = tobf(v.w);
  *(bf16x4*)(d + off) = o;
}

// K-split projection GEMM: grid (32 m, 32 nseg, 2 kh); bf16 partials.
__global__ __launch_bounds__(256) void k_projA(
    const bf16* __restrict__ hsb,
    const bf16* __restrict__ Wqb, const bf16* __restrict__ Wkb,
    const bf16* __restrict__ Wgb, const bf16* __restrict__ Wvb,
    bf16* __restrict__ pbuf)
{
  __shared__ __align__(16) bf16 sA[2 * 128 * 32];
  __shared__ __align__(16) bf16 sB[2 * 128 * 32];
  const int m0 = blockIdx.x * 128;
  const int nseg = blockIdx.y;          // 0..31
  const int kh = blockIdx.z;            // 0..1
  const int seg = nseg >> 3;
  const int n0 = (nseg & 7) * 128;
  const bf16* W = seg == 0 ? Wqb : seg == 1 ? Wkb : seg == 2 ? Wgb : Wvb;
  const int tid = threadIdx.x, lane = tid & 63;
  const int wr = (tid >> 6) >> 1, wc = (tid >> 6) & 1;
  f32x4 acc[16];
#pragma unroll
  for (int i = 0; i < 16; ++i) acc[i] = fzero();
  gemm_core<128, 128>(hsb + kh * 1024, H_, m0, W + kh * 1024, H_, n0, 1024,
                      acc, sA, sB, tid);
  bf16* dst = pbuf + (size_t)kh * T_ * 4096;
#pragma unroll
  for (int m = 0; m < 4; ++m)
#pragma unroll
    for (int n = 0; n < 4; ++n) {
      f32x4 v = acc[m * 4 + n];
      int colF = seg * 1024 + n0 + wc * 64 + n * 16 + (lane & 15);
#pragma unroll
      for (int r = 0; r < 4; ++r) {
        int row = m0 + wr * 64 + m * 16 + (lane >> 4) * 4 + r;
        dst[(size_t)row * 4096 + colF] = tobf(v[r]);
      }
    }
}

// reduce partials + bias + activations -> qb / kb / la / vb
__global__ __launch_bounds__(256) void k_projB(
    const bf16* __restrict__ pbuf,
    const float* __restrict__ bq, const float* __restrict__ bk,
    const float* __restrict__ bg, const float* __restrict__ bv,
    bf16* __restrict__ qb, bf16* __restrict__ kb,
    float* __restrict__ la, bf16* __restrict__ vb)
{
  size_t i = ((size_t)blockIdx.x * 256 + threadIdx.x) * 8;   // over T_*4096
  int row = (int)(i >> 12), colF = (int)(i & 4095);
  int seg = colF >> 10, col = colF & 1023;
  bf16x8 p0 = *(const bf16x8*)(pbuf + i);
  bf16x8 p1 = *(const bf16x8*)(pbuf + (size_t)T_ * 4096 + i);
  const float* bias = seg == 0 ? bq : seg == 1 ? bk : seg == 2 ? bg : bv;
  float4 b0 = *(const float4*)(bias + col);
  float4 b1 = *(const float4*)(bias + col + 4);
  float x[8];
#pragma unroll
  for (int j = 0; j < 8; ++j) {
    float b = j < 4 ? (&b0.x)[j] : (&b1.x)[j - 4];
    x[j] = (float)p0[j] + (float)p1[j] + b;
  }
  size_t o = (size_t)row * KD + col;
  if (seg == 2) {
    float4 o0, o1;
#pragma unroll
    for (int j = 0; j < 4; ++j)
      (&o0.x)[j] = fminf(x[j], 0.f) - log1pf(expf(-fabsf(x[j])));
#pragma unroll
    for (int j = 0; j < 4; ++j)
      (&o1.x)[j] = fminf(x[4 + j], 0.f) - log1pf(expf(-fabsf(x[4 + j])));
    *(float4*)(la + o) = o0; *(float4*)(la + o + 4) = o1;
  } else {
    bf16x8 ov;
#pragma unroll
    for (int j = 0; j < 8; ++j) {
      float y = (seg == 1) ? 1.f / (1.f + expf(-x[j])) : x[j];
      ov[j] = tobf(y);
    }
    bf16* dst = seg == 0 ? qb : seg == 1 ? kb : vb;
    *(bf16x8*)(dst + o) = ov;
  }
}

// path0: fused within-chunk prefix of log g + decay-weighted operands.
// path1: V^T [c][vv][t].
__global__ __launch_bounds__(256) void k_transform(
    const bf16* __restrict__ qb, const bf16* __restrict__ kb,
    const float* __restrict__ la, const bf16* __restrict__ vb,
    bf16* __restrict__ qt, bf16* __restrict__ kt,
    bf16* __restrict__ kbarT, bf16* __restrict__ vT,
    float* __restrict__ laC)
{
  __shared__ bf16 tr[64][72];
  __shared__ float gtot[4][64];
  const int c = blockIdx.y, tile = blockIdx.x, path = blockIdx.z;
  const int tid = threadIdx.x;
  const int colL = tid & 63;
  const int grp = tid >> 6;            // 0..3
  if (path == 0) {
    const int kk0 = tile * 64;
    const int kk = kk0 + colL;
    float lraw[16];
    float run = 0.f;
#pragma unroll
    for (int i = 0; i < 16; ++i) {
      int t = grp * 16 + i;
      lraw[i] = la[(size_t)(c * CH + t) * KD + kk];
      run += lraw[i];
    }
    gtot[grp][colL] = run;
    __syncthreads();
    float off = 0.f, lc = 0.f;
#pragma unroll
    for (int g2 = 0; g2 < 4; ++g2) {
      float v = gtot[g2][colL];
      if (g2 < grp) off += v;
      lc += v;
    }
    if (grp == 0) laC[(size_t)c * KD + kk] = lc;
    float run2 = off;
#pragma unroll
    for (int i = 0; i < 16; ++i) {
      int t = grp * 16 + i;
      run2 += lraw[i];
      size_t idx = (size_t)(c * CH + t) * KD + kk;
      float qv = (float)qb[idx];
      float kv = (float)kb[idx];
      qt[idx] = tobf(qv * expf(run2));
      kt[idx] = tobf(kv * expf(-run2));
      tr[colL][t] = tobf(kv * expf(lc - run2));   // kbar, staged for transpose
    }
    __syncthreads();
#pragma unroll
    for (int i = 0; i < 16; ++i) {
      int row = grp + 4 * i;
      kbarT[((size_t)c * KD + kk0 + row) * 64 + colL] = tr[row][colL];
    }
  } else {
    const int vv0 = tile * 64;
#pragma unroll
    for (int i = 0; i < 16; ++i) {
      int t = grp + 4 * i;
      tr[colL][t] = vb[(size_t)(c * CH + t) * VD + vv0 + colL];
    }
    __syncthreads();
#pragma unroll
    for (int i = 0; i < 16; ++i) {
      int row = grp + 4 * i;
      vT[((size_t)c * VD + vv0 + row) * 64 + colL] = tr[row][colL];
    }
  }
}

// K-split QK^T partials: Ppart[c][ks] = q~ slice @ k~ slice^T (fp32)
__global__ __launch_bounds__(256) void k_qkt(
    const bf16* __restrict__ qt, const bf16* __restrict__ kt,
    float* __restrict__ Ppart)
{
  __shared__ __align__(16) bf16 sA[2 * 64 * 32];
  __shared__ __align__(16) bf16 sB[2 * 64 * 32];
  const int ks = blockIdx.x, c = blockIdx.y;
  const int tid = threadIdx.x, lane = tid & 63;
  const int wr = (tid >> 6) >> 1, wc = (tid >> 6) & 1;
  f32x4 acc[4];
#pragma unroll
  for (int i = 0; i < 4; ++i) acc[i] = fzero();
  gemm_core<64, 64>(qt + (size_t)c * CH * KD + ks * 256, KD, 0,
                    kt + (size_t)c * CH * KD + ks * 256, KD, 0, 256,
                    acc, sA, sB, tid);
  float* dst = Ppart + ((size_t)c * 4 + ks) * 4096;
#pragma unroll
  for (int m = 0; m < 2; ++m)
#pragma unroll
    for (int n = 0; n < 2; ++n) {
      f32x4 v = acc[m * 2 + n];
      int j = wc * 32 + n * 16 + (lane & 15);
#pragma unroll
      for (int r = 0; r < 4; ++r) {
        int t = wr * 32 + m * 16 + (lane >> 4) * 4 + r;
        dst[t * 64 + j] = v[r];
      }
    }
}

// U^T[vv][kk] = sum_j V[j,vv] kbar[j,kk]  -> ustore slot (bf16)
__global__ __launch_bounds__(256) void k_ugemm(
    const bf16* __restrict__ vT, const bf16* __restrict__ kbarT,
    bf16* __restrict__ ustore, int g)
{
  __shared__ __align__(16) bf16 sA[2 * 128 * 32];
  __shared__ __align__(16) bf16 sB[2 * 128 * 32];
  const int cl = blockIdx.z, c = g * CPG + cl;
  const int m0 = blockIdx.x * 128, n0 = blockIdx.y * 128;
  const int tid = threadIdx.x, lane = tid & 63;
  const int wr = (tid >> 6) >> 1, wc = (tid >> 6) & 1;
  f32x4 acc[16];
#pragma unroll
  for (int i = 0; i < 16; ++i) acc[i] = fzero();
  gemm_core<128, 128>(vT + (size_t)c * VD * 64, 64, m0,
                      kbarT + (size_t)c * KD * 64, 64, n0, 64, acc, sA, sB, tid);
  bf16* dst = ustore + (size_t)cl * KD * VD;
#pragma unroll
  for (int m = 0; m < 4; ++m)
#pragma unroll
    for (int n = 0; n < 4; ++n) {
      f32x4 v = acc[m * 4 + n];
      int col = wc * 64 + n * 16 + (lane & 15);
#pragma unroll
      for (int r = 0; r < 4; ++r) {
        int row = wr * 64 + m * 16 + (lane >> 4) * 4 + r;
        dst[(size_t)(m0 + row) * KD + n0 + col] = tobf(v[r]);
      }
    }
}

// elementwise scan over chunks — vectorized bf16x8 (8 kk per thread)
__global__ __launch_bounds__(256) void k_scan(
    bf16* __restrict__ ustore, const float* __restrict__ laC,
    float* __restrict__ Sinit, bf16* __restrict__ ScarryB,
    float* __restrict__ dstate, int g)
{
  __shared__ float tl[64][132];
  const int vv0 = blockIdx.x * 64, kk0 = blockIdx.y * 128;
  const int tid = threadIdx.x;
  const int kv = (tid & 15) * 8;
  const int vr = tid >> 4;
  float s[4][8];
  if (g == 0) {
#pragma unroll
    for (int i = 0; i < 4; ++i)
#pragma unroll
      for (int j = 0; j < 8; ++j) s[i][j] = 0.f;
  } else {
#pragma unroll
    for (int i = 0; i < 4; ++i) {
      const float* p = Sinit + (size_t)(vv0 + vr + 16 * i) * KD + kk0 + kv;
      float4 a = *(const float4*)p, b = *(const float4*)(p + 4);
      s[i][0]=a.x; s[i][1]=a.y; s[i][2]=a.z; s[i][3]=a.w;
      s[i][4]=b.x; s[i][5]=b.y; s[i][6]=b.z; s[i][7]=b.w;
    }
  }
  for (int cl = 0; cl < CPG; ++cl) {
    int c = g * CPG + cl;
    const float* lp = laC + (size_t)c * KD + kk0 + kv;
    float4 la0 = *(const float4*)lp, la1 = *(const float4*)(lp + 4);
    float d[8] = {expf(la0.x), expf(la0.y), expf(la0.z), expf(la0.w),
                  expf(la1.x), expf(la1.y), expf(la1.z), expf(la1.w)};
    size_t base = (size_t)cl * KD * VD;
#pragma unroll
    for (int i = 0; i < 4; ++i) {
      bf16* up = ustore + base + (size_t)(vv0 + vr + 16 * i) * KD + kk0 + kv;
      bf16x8 u = *(const bf16x8*)up;
      bf16x8 o;
#pragma unroll
      for (int j = 0; j < 8; ++j) {
        s[i][j] = fmaf(d[j], s[i][j], (float)u[j]);
        o[j] = tobf(s[i][j]);
      }
      *(bf16x8*)up = o;
    }
  }
  if (g < NGROUP - 1) {
#pragma unroll
    for (int i = 0; i < 4; ++i) {
      float* p = Sinit + (size_t)(vv0 + vr + 16 * i) * KD + kk0 + kv;
      bf16* pb = ScarryB + (size_t)(vv0 + vr + 16 * i) * KD + kk0 + kv;
      float4 a = {s[i][0], s[i][1], s[i][2], s[i][3]};
      float4 b = {s[i][4], s[i][5], s[i][6], s[i][7]};
      *(float4*)p = a; *(float4*)(p + 4) = b;
      bf16x8 o;
#pragma unroll
      for (int j = 0; j < 8; ++j) o[j] = tobf(s[i][j]);
      *(bf16x8*)pb = o;
    }
  } else {
#pragma unroll
    for (int i = 0; i < 4; ++i)
#pragma unroll
      for (int j = 0; j < 8; ++j) tl[vr + 16 * i][kv + j] = s[i][j];
    __syncthreads();
    const int kkL = tid >> 1;
    const int vvh = (tid & 1) * 32;
    float* dp = dstate + (size_t)(kk0 + kkL) * VD + vv0 + vvh;
#pragma unroll
    for (int j4 = 0; j4 < 8; ++j4) {
      float4 o2 = {tl[vvh + j4 * 4 + 0][kkL], tl[vvh + j4 * 4 + 1][kkL],
                   tl[vvh + j4 * 4 + 2][kkL], tl[vvh + j4 * 4 + 3][kkL]};
      *(float4*)(dp + j4 * 4) = o2;
    }
  }
}

// fused: P assemble + inter GEMM (q~_c @ S_{c-1}) + PV (64-col slice)
// -> ob = bf16(intra + inter). grid (16 ntiles, CPG chunks) = 512 blocks.
__global__ __launch_bounds__(256) void k_inter2(
    const bf16* __restrict__ qt, const float* __restrict__ Ppart,
    const bf16* __restrict__ vT, const bf16* __restrict__ ustore,
    const bf16* __restrict__ ScarryB, bf16* __restrict__ ob, int g)
{
  __shared__ __align__(16) bf16 sA[2 * 64 * 32];    // 8 KB
  __shared__ __align__(16) bf16 sB[2 * 64 * 32];    // 8 KB
  __shared__ __align__(16) bf16 Pl[64 * 72];        // 9 KB
  __shared__ __align__(16) bf16 sV[64 * 72];        // 9 KB
  const int cl = blockIdx.y, c = g * CPG + cl;
  const int n0 = blockIdx.x * 64;
  const int tid = threadIdx.x, lane = tid & 63;
  const int wr = (tid >> 6) >> 1, wc = (tid >> 6) & 1;

  // assemble P = sum of 4 K-partials, causal mask, bf16 into Pl
  {
    const float* base = Ppart + (size_t)c * 4 * 4096;
    const int i0 = tid * 16;
    const int t = tid >> 2;
    const int j0 = (tid & 3) * 16;
#pragma unroll
    for (int e = 0; e < 16; e += 4) {
      float4 s0 = *(const float4*)(base + 0 * 4096 + i0 + e);
      float4 s1 = *(const float4*)(base + 1 * 4096 + i0 + e);
      float4 s2 = *(const float4*)(base + 2 * 4096 + i0 + e);
      float4 s3 = *(const float4*)(base + 3 * 4096 + i0 + e);
      float sx = s0.x + s1.x + s2.x + s3.x;
      float sy = s0.y + s1.y + s2.y + s3.y;
      float sz = s0.z + s1.z + s2.z + s3.z;
      float sw = s0.w + s1.w + s2.w + s3.w;
      int j = j0 + e;
      Pl[t * 72 + j + 0] = (j + 0 <= t) ? tobf(sx) : tobf(0.f);
      Pl[t * 72 + j + 1] = (j + 1 <= t) ? tobf(sy) : tobf(0.f);
      Pl[t * 72 + j + 2] = (j + 2 <= t) ? tobf(sz) : tobf(0.f);
      Pl[t * 72 + j + 3] = (j + 3 <= t) ? tobf(sw) : tobf(0.f);
    }
  }
  __syncthreads();

  f32x4 acc[4];
#pragma unroll
  for (int i = 0; i < 4; ++i) acc[i] = fzero();
  if (c > 0) {
    const bf16* B = (cl == 0) ? ScarryB : ustore + (size_t)(cl - 1) * KD * VD;
    gemm_core<64, 64>(qt + (size_t)c * CH * KD, KD, 0, B, KD, n0, KD,
                      acc, sA, sB, tid);
  }

  // stage V^T slice rows [n0, n0+64) and add PV into acc
#pragma unroll
  for (int rr = 0; rr < 2; ++rr) {
    int idx = rr * 256 + tid;
    int row = idx >> 3;
    int j0 = (idx & 7) * 8;
    bf16x8 vv = *(const bf16x8*)(vT + ((size_t)c * VD + n0 + row) * 64 + j0);
    *(bf16x8*)(sV + row * 72 + j0) = vv;
  }
  __syncthreads();
#pragma unroll
  for (int ks = 0; ks < 64; ks += 32) {
    bf16x8 af[2], bfr[2];
#pragma unroll
    for (int m = 0; m < 2; ++m)
      af[m] = *(const bf16x8*)(Pl + (wr * 32 + m * 16 + (lane & 15)) * 72
                               + ks + (lane >> 4) * 8);
#pragma unroll
    for (int n = 0; n < 2; ++n)
      bfr[n] = *(const bf16x8*)(sV + (wc * 32 + n * 16 + (lane & 15)) * 72
                                + ks + (lane >> 4) * 8);
#pragma unroll
    for (int m = 0; m < 2; ++m)
#pragma unroll
      for (int n = 0; n < 2; ++n)
        acc[m * 2 + n] = __builtin_amdgcn_mfma_f32_16x16x32_bf16(
            af[m], bfr[n], acc[m * 2 + n], 0, 0, 0);
  }

#pragma unroll
  for (int m = 0; m < 2; ++m)
#pragma unroll
    for (int n = 0; n < 2; ++n) {
      f32x4 v = acc[m * 2 + n];
      int col = wc * 32 + n * 16 + (lane & 15);
#pragma unroll
      for (int r = 0; r < 4; ++r) {
        int row = wr * 32 + m * 16 + (lane >> 4) * 4 + r;
        ob[((size_t)c * CH + row) * VD + n0 + col] = tobf(v[r]);
      }
    }
}

// y partials: K-split x2 over VD. grid (32, 16, 2) = 1024 blocks.
__global__ __launch_bounds__(256) void k_outA(
    const bf16* __restrict__ ob, const bf16* __restrict__ Wob,
    float* __restrict__ fpart)
{
  __shared__ __align__(16) bf16 sA[2 * 128 * 32];
  __shared__ __align__(16) bf16 sB[2 * 128 * 32];
  const int m0 = blockIdx.x * 128, n0 = blockIdx.y * 128;
  const int kh = blockIdx.z;
  const int tid = threadIdx.x, lane = tid & 63;
  const int wr = (tid >> 6) >> 1, wc = (tid >> 6) & 1;
  f32x4 acc[16];
#pragma unroll
  for (int i = 0; i < 16; ++i) acc[i] = fzero();
  gemm_core<128, 128>(ob + kh * 512, VD, m0, Wob + kh * 512, VD, n0, 512,
                      acc, sA, sB, tid);
  float* dst = fpart + (size_t)kh * T_ * OD;
#pragma unroll
  for (int m = 0; m < 4; ++m)
#pragma unroll
    for (int n = 0; n < 4; ++n) {
      f32x4 v = acc[m * 4 + n];
      int col = n0 + wc * 64 + n * 16 + (lane & 15);
#pragma unroll
      for (int r = 0; r < 4; ++r) {
        int row = m0 + wr * 64 + m * 16 + (lane >> 4) * 4 + r;
        dst[(size_t)row * OD + col] = v[r];
      }
    }
}

// reduce fp32 partials + bias -> out
__global__ __launch_bounds__(256) void k_outB(
    const float* __restrict__ fpart, const float* __restrict__ bo,
    float* __restrict__ out)
{
  size_t i = ((size_t)blockIdx.x * 256 + threadIdx.x) * 4;   // over T_*OD
  int col = (int)(i & (OD - 1));
  float4 p0 = *(const float4*)(fpart + i);
  float4 p1 = *(const float4*)(fpart + (size_t)T_ * OD + i);
  float4 b  = *(const float4*)(bo + col);
  float4 o;
  o.x = p0.x + p1.x + b.x; o.y = p0.y + p1.y + b.y;
  o.z = p0.z + p1.z + b.z; o.w = p0.w + p1.w + b.w;
  *(float4*)(out + i) = o;
}

// ---------------------------------------------------------------------------
extern "C" void kernel_launch(void* const* d_in, const int* in_sizes, int n_in,
                              void* d_out, int out_size, void* d_ws, size_t ws_size,
                              hipStream_t stream)
{
  const float* hs = (const float*)d_in[0];
  const float* Wq = (const float*)d_in[1];
  const float* bq = (const float*)d_in[2];
  const float* Wk = (const float*)d_in[3];
  const float* bk = (const float*)d_in[4];
  const float* Wv = (const float*)d_in[5];
  const float* bv = (const float*)d_in[6];
  const float* Wg = (const float*)d_in[7];
  const float* bg = (const float*)d_in[8];
  const float* Wo = (const float*)d_in[9];
  const float* bo = (const float*)d_in[10];
  float* out = (float*)d_out;
  float* dstate = out + (size_t)T_ * OD;

  char* p = (char*)d_ws;
  auto alloc = [&](size_t b) -> char* {
    char* r = p; p += (b + 255) & ~(size_t)255; return r;
  };
  bf16* hsb    = (bf16*)alloc((size_t)T_ * H_ * 2);
  bf16* Wqb    = (bf16*)alloc((size_t)KD * H_ * 2);
  bf16* Wkb    = (bf16*)alloc((size_t)KD * H_ * 2);
  bf16* Wgb    = (bf16*)alloc((size_t)KD * H_ * 2);
  bf16* Wvb    = (bf16*)alloc((size_t)VD * H_ * 2);
  bf16* Wob    = (bf16*)alloc((size_t)OD * VD * 2);
  bf16* qb     = (bf16*)alloc((size_t)T_ * KD * 2);
  bf16* kb     = (bf16*)alloc((size_t)T_ * KD * 2);
  float* la    = (float*)alloc((size_t)T_ * KD * 4);
  bf16* vb     = (bf16*)alloc((size_t)T_ * VD * 2);
  bf16* qt     = (bf16*)alloc((size_t)T_ * KD * 2);
  bf16* kt     = (bf16*)alloc((size_t)T_ * KD * 2);
  bf16* kbarT  = (bf16*)alloc((size_t)T_ * KD * 2);
  bf16* vT     = (bf16*)alloc((size_t)T_ * VD * 2);
  bf16* ob     = (bf16*)alloc((size_t)T_ * VD * 2);
  float* Sinit = (float*)alloc((size_t)KD * VD * 4);
  bf16* ScarryB= (bf16*)alloc((size_t)KD * VD * 2);
  bf16* ustore = (bf16*)alloc((size_t)CPG * KD * VD * 2);   // 64 MB
  float* laC   = (float*)alloc((size_t)NCHUNK * KD * 4);
  float* Ppart = (float*)alloc((size_t)NCHUNK * 4 * 4096 * 4);
  if ((size_t)(p - (char*)d_ws) > ws_size) return;

  // pbuf (proj partials, 64MB bf16) and fpart (out partials, 64MB fp32)
  // both reuse ustore: free before k_ugemm / after last k_inter2.
  bf16* pbuf = ustore;
  float* fpart = (float*)ustore;

  k_cvt6<<<(int)((CVT_TOT / 4 + 255) / 256), 256, 0, stream>>>(
      hs, Wq, Wk, Wg, Wv, Wo, hsb, Wqb, Wkb, Wgb, Wvb, Wob);

  k_projA<<<dim3(T_ / 128, 32, 2), 256, 0, stream>>>(
      hsb, Wqb, Wkb, Wgb, Wvb, pbuf);
  k_projB<<<(int)((size_t)T_ * 4096 / 8 / 256), 256, 0, stream>>>(
      pbuf, bq, bk, bg, bv, qb, kb, la, vb);

  k_transform<<<dim3(16, NCHUNK, 2), 256, 0, stream>>>(
      qb, kb, la, vb, qt, kt, kbarT, vT, laC);

  k_qkt<<<dim3(4, NCHUNK), 256, 0, stream>>>(qt, kt, Ppart);

  for (int g = 0; g < NGROUP; ++g) {
    k_ugemm<<<dim3(8, 8, CPG), 256, 0, stream>>>(vT, kbarT, ustore, g);
    k_scan<<<dim3(16, 8), 256, 0, stream>>>(ustore, laC, Sinit, ScarryB, dstate, g);
    k_inter2<<<dim3(16, CPG), 256, 0, stream>>>(
        qt, Ppart, vT, ustore, ScarryB, ob, g);
  }

  k_outA<<<dim3(T_ / 128, OD / 128, 2), 256, 0, stream>>>(ob, Wob, fpart);
  k_outB<<<(int)((size_t)T_ * OD / 4 / 256), 256, 0, stream>>>(fpart, bo, out);
}

// Round 9
// 291.538 us; speedup vs baseline: 1.3914x; 1.3914x over previous
//
#include <hip/hip_runtime.h>
#include <stdint.h>
#include <stddef.h>

// ---------------------------------------------------------------------------
// SimpleRNN (gated linear attention) — chunked parallel formulation.
//   q = hs@Wq^T+bq ; k = sig(hs@Wk^T+bk) ; g = sig(hs@Wg^T+bg) ; v = hs@Wv^T+bv
//   S_t = diag(g_t) S_{t-1} + k_t v_t^T ; out_t = q_t S_t ; y = out@Wo^T+bo
// Chunked (C=64): la = within-chunk cumsum(log g) [fused in k_transform],
//   q~ = q*exp(la), k~ = k*exp(-la), kbar = k*exp(laC-la)
//   out = tril(q~ k~^T) V  +  q~ @ S_prev
//   U_c = kbar^T V ;  S_c = exp(laC) (.) S_{c-1} + U_c
//
// R9: R7 base (3-buf counted gemm_core = best measured). k_ugemm+k_scan fused
// into k_uscan: S lives in the MFMA accumulator (fp32 across chunks), decay
// pre-scale per chunk, MFMA accumulates U_c into S, write S_c bf16 per chunk.
// k_out -> BN=64 (1024 blocks, 4/CU) per R7's concurrency lesson.
// ---------------------------------------------------------------------------

#define DEVI __device__ __forceinline__

typedef __bf16 bf16;
typedef __bf16 bf16x8 __attribute__((ext_vector_type(8)));
typedef __bf16 bf16x4 __attribute__((ext_vector_type(4)));
typedef float  f32x4  __attribute__((ext_vector_type(4)));

static constexpr int T_  = 4096;
static constexpr int H_  = 2048;
static constexpr int KD  = 1024;
static constexpr int VD  = 1024;
static constexpr int OD  = 2048;
static constexpr int CH  = 64;                 // chunk length
static constexpr int NCHUNK = T_ / CH;         // 64
static constexpr int NGROUP = 2;               // chunk groups (ws economy)
static constexpr int CPG    = NCHUNK / NGROUP; // 32

DEVI bf16 tobf(float f) {
  union { float f; uint32_t u; } x; x.f = f;
  uint32_t r = (x.u + 0x7FFFu + ((x.u >> 16) & 1u)) >> 16;  // RNE
  union { uint16_t s; bf16 b; } y; y.s = (uint16_t)r;
  return y.b;
}

DEVI f32x4 fzero() { f32x4 z = {0.f, 0.f, 0.f, 0.f}; return z; }

// async global->LDS, 16B per lane (lane-linear LDS destination).
DEVI void gld16(const bf16* g, bf16* l) {
  auto* g1 = reinterpret_cast<__attribute__((address_space(1))) uint32_t*>(
      (uintptr_t)g);
  auto* l3 = reinterpret_cast<__attribute__((address_space(3))) uint32_t*>(
      (uintptr_t)l);
  __builtin_amdgcn_global_load_lds(g1, l3, 16, 0, 0);
}

template<int N> DEVI void waitvm() {
  if constexpr (N == 0) asm volatile("s_waitcnt vmcnt(0)" ::: "memory");
  else if constexpr (N == 2) asm volatile("s_waitcnt vmcnt(2)" ::: "memory");
  else if constexpr (N == 3) asm volatile("s_waitcnt vmcnt(3)" ::: "memory");
  else if constexpr (N == 4) asm volatile("s_waitcnt vmcnt(4)" ::: "memory");
  else static_assert(N == 0, "unsupported vmcnt");
}

// C[m0..+BM, n0..+BN] += A[M,K] * B[N,K]^T, both row-major K-contiguous.
// 4 waves in 2x2; BK=32; 3-buffer counted pipeline (R5/R7 — best measured).
template<int BM, int BN>
DEVI void gemm_core(const bf16* A, int lda, int m0,
                    const bf16* B, int ldb, int n0,
                    int K, f32x4* acc, bf16* sA, bf16* sB, int tid)
{
  constexpr int MR = BM / 32;
  constexpr int NR = BN / 32;
  constexpr int ASZ = BM * 32;
  constexpr int BSZ = BN * 32;
  constexpr int LOADS = BM / 64 + BN / 64;
  const int lane = tid & 63;
  const int wr = (tid >> 6) >> 1;
  const int wc = (tid >> 6) & 1;
  const int srow = tid >> 2;
  const int skof = (tid & 3) * 8;
  const bf16* aB = A + (size_t)(m0 + srow) * lda + skof;
  const bf16* bB = B + (size_t)(n0 + srow) * ldb + skof;

  auto stage = [&](int t, int buf) {
    const int k0 = t * 32;
#pragma unroll
    for (int r = 0; r < BM / 64; ++r)
      gld16(aB + (size_t)r * 64 * lda + k0, sA + buf * ASZ + r * 2048 + tid * 8);
#pragma unroll
    for (int r = 0; r < BN / 64; ++r)
      gld16(bB + (size_t)r * 64 * ldb + k0, sB + buf * BSZ + r * 2048 + tid * 8);
  };

  const int nt = K / 32;
  stage(0, 0);
  if (nt > 1) stage(1, 1);
  int cur = 0;
  for (int t = 0; t < nt; ++t) {
    if (t < nt - 1) waitvm<LOADS>();
    else            waitvm<0>();
    __builtin_amdgcn_s_barrier();
    __builtin_amdgcn_sched_barrier(0);
    if (t + 2 < nt) {
      int b2 = cur + 2; if (b2 >= 3) b2 -= 3;
      stage(t + 2, b2);
    }
    const bf16* pA = sA + cur * ASZ;
    const bf16* pB = sB + cur * BSZ;
    bf16x8 af[MR], bfr[NR];
#pragma unroll
    for (int m = 0; m < MR; ++m)
      af[m] = *(const bf16x8*)(pA + (wr * (MR * 16) + m * 16 + (lane & 15)) * 32
                               + (lane >> 4) * 8);
#pragma unroll
    for (int n = 0; n < NR; ++n)
      bfr[n] = *(const bf16x8*)(pB + (wc * (NR * 16) + n * 16 + (lane & 15)) * 32
                                + (lane >> 4) * 8);
#pragma unroll
    for (int m = 0; m < MR; ++m)
#pragma unroll
      for (int n = 0; n < NR; ++n)
        acc[m * NR + n] = __builtin_amdgcn_mfma_f32_16x16x32_bf16(
            af[m], bfr[n], acc[m * NR + n], 0, 0, 0);
    ++cur; if (cur >= 3) cur -= 3;
  }
}

// ---------------------------------------------------------------------------
static constexpr size_t CVT_HS = (size_t)T_ * H_;
static constexpr size_t CVT_W  = (size_t)KD * H_;
static constexpr size_t CVT_WO = (size_t)OD * VD;
static constexpr size_t CVT_TOT = CVT_HS + 4 * CVT_W + CVT_WO;

__global__ __launch_bounds__(256) void k_cvt6(
    const float* __restrict__ hs, const float* __restrict__ Wq,
    const float* __restrict__ Wk, const float* __restrict__ Wg,
    const float* __restrict__ Wv, const float* __restrict__ Wo,
    bf16* __restrict__ hsb, bf16* __restrict__ Wqb,
    bf16* __restrict__ Wkb, bf16* __restrict__ Wgb,
    bf16* __restrict__ Wvb, bf16* __restrict__ Wob)
{
  size_t i = ((size_t)blockIdx.x * 256 + threadIdx.x) * 4;
  if (i >= CVT_TOT) return;
  const float* s; bf16* d; size_t off;
  if (i < CVT_HS)                { s = hs; d = hsb; off = i; }
  else if (i < CVT_HS + CVT_W)   { s = Wq; d = Wqb; off = i - CVT_HS; }
  else if (i < CVT_HS + 2*CVT_W) { s = Wk; d = Wkb; off = i - CVT_HS - CVT_W; }
  else if (i < CVT_HS + 3*CVT_W) { s = Wg; d = Wgb; off = i - CVT_HS - 2*CVT_W; }
  else if (i < CVT_HS + 4*CVT_W) { s = Wv; d = Wvb; off = i - CVT_HS - 3*CVT_W; }
  else                           { s = Wo; d = Wob; off = i - CVT_HS - 4*CVT_W; }
  float4 v = *(const float4*)(s + off);
  bf16x4 o; o[0] = tobf(v.x); o[1] = tobf(v.y); o[2] = tobf(v.z); o[3] = tobf(v.w);
  *(bf16x4*)(d + off) = o;
}

// K-split projection GEMM: grid (32 m, 32 nseg, 2 kh); bf16 partials.
__global__ __launch_bounds__(256) void k_projA(
    const bf16* __restrict__ hsb,
    const bf16* __restrict__ Wqb, const bf16* __restrict__ Wkb,
    const bf16* __restrict__ Wgb, const bf16* __restrict__ Wvb,
    bf16* __restrict__ pbuf)
{
  __shared__ __align__(16) bf16 sA[3 * 128 * 32];
  __shared__ __align__(16) bf16 sB[3 * 128 * 32];
  const int m0 = blockIdx.x * 128;
  const int nseg = blockIdx.y;          // 0..31
  const int kh = blockIdx.z;            // 0..1
  const int seg = nseg >> 3;
  const int n0 = (nseg & 7) * 128;
  const bf16* W = seg == 0 ? Wqb : seg == 1 ? Wkb : seg == 2 ? Wgb : Wvb;
  const int tid = threadIdx.x, lane = tid & 63;
  const int wr = (tid >> 6) >> 1, wc = (tid >> 6) & 1;
  f32x4 acc[16];
#pragma unroll
  for (int i = 0; i < 16; ++i) acc[i] = fzero();
  gemm_core<128, 128>(hsb + kh * 1024, H_, m0, W + kh * 1024, H_, n0, 1024,
                      acc, sA, sB, tid);
  bf16* dst = pbuf + (size_t)kh * T_ * 4096;
#pragma unroll
  for (int m = 0; m < 4; ++m)
#pragma unroll
    for (int n = 0; n < 4; ++n) {
      f32x4 v = acc[m * 4 + n];
      int colF = seg * 1024 + n0 + wc * 64 + n * 16 + (lane & 15);
#pragma unroll
      for (int r = 0; r < 4; ++r) {
        int row = m0 + wr * 64 + m * 16 + (lane >> 4) * 4 + r;
        dst[(size_t)row * 4096 + colF] = tobf(v[r]);
      }
    }
}

// reduce partials + bias + activations -> qb / kb / la / vb
__global__ __launch_bounds__(256) void k_projB(
    const bf16* __restrict__ pbuf,
    const float* __restrict__ bq, const float* __restrict__ bk,
    const float* __restrict__ bg, const float* __restrict__ bv,
    bf16* __restrict__ qb, bf16* __restrict__ kb,
    float* __restrict__ la, bf16* __restrict__ vb)
{
  size_t i = ((size_t)blockIdx.x * 256 + threadIdx.x) * 8;   // over T_*4096
  int row = (int)(i >> 12), colF = (int)(i & 4095);
  int seg = colF >> 10, col = colF & 1023;
  bf16x8 p0 = *(const bf16x8*)(pbuf + i);
  bf16x8 p1 = *(const bf16x8*)(pbuf + (size_t)T_ * 4096 + i);
  const float* bias = seg == 0 ? bq : seg == 1 ? bk : seg == 2 ? bg : bv;
  float4 b0 = *(const float4*)(bias + col);
  float4 b1 = *(const float4*)(bias + col + 4);
  float x[8];
#pragma unroll
  for (int j = 0; j < 8; ++j) {
    float b = j < 4 ? (&b0.x)[j] : (&b1.x)[j - 4];
    x[j] = (float)p0[j] + (float)p1[j] + b;
  }
  size_t o = (size_t)row * KD + col;
  if (seg == 2) {
    float4 o0, o1;
#pragma unroll
    for (int j = 0; j < 4; ++j)
      (&o0.x)[j] = fminf(x[j], 0.f) - log1pf(expf(-fabsf(x[j])));
#pragma unroll
    for (int j = 0; j < 4; ++j)
      (&o1.x)[j] = fminf(x[4 + j], 0.f) - log1pf(expf(-fabsf(x[4 + j])));
    *(float4*)(la + o) = o0; *(float4*)(la + o + 4) = o1;
  } else {
    bf16x8 ov;
#pragma unroll
    for (int j = 0; j < 8; ++j) {
      float y = (seg == 1) ? 1.f / (1.f + expf(-x[j])) : x[j];
      ov[j] = tobf(y);
    }
    bf16* dst = seg == 0 ? qb : seg == 1 ? kb : vb;
    *(bf16x8*)(dst + o) = ov;
  }
}

// path0: fused within-chunk prefix of log g + decay-weighted operands.
// path1: V^T [c][vv][t].
__global__ __launch_bounds__(256) void k_transform(
    const bf16* __restrict__ qb, const bf16* __restrict__ kb,
    const float* __restrict__ la, const bf16* __restrict__ vb,
    bf16* __restrict__ qt, bf16* __restrict__ kt,
    bf16* __restrict__ kbarT, bf16* __restrict__ vT,
    float* __restrict__ laC)
{
  __shared__ bf16 tr[64][72];
  __shared__ float gtot[4][64];
  const int c = blockIdx.y, tile = blockIdx.x, path = blockIdx.z;
  const int tid = threadIdx.x;
  const int colL = tid & 63;
  const int grp = tid >> 6;            // 0..3
  if (path == 0) {
    const int kk0 = tile * 64;
    const int kk = kk0 + colL;
    float lraw[16];
    float run = 0.f;
#pragma unroll
    for (int i = 0; i < 16; ++i) {
      int t = grp * 16 + i;
      lraw[i] = la[(size_t)(c * CH + t) * KD + kk];
      run += lraw[i];
    }
    gtot[grp][colL] = run;
    __syncthreads();
    float off = 0.f, lc = 0.f;
#pragma unroll
    for (int g2 = 0; g2 < 4; ++g2) {
      float v = gtot[g2][colL];
      if (g2 < grp) off += v;
      lc += v;
    }
    if (grp == 0) laC[(size_t)c * KD + kk] = lc;
    float run2 = off;
#pragma unroll
    for (int i = 0; i < 16; ++i) {
      int t = grp * 16 + i;
      run2 += lraw[i];
      size_t idx = (size_t)(c * CH + t) * KD + kk;
      float qv = (float)qb[idx];
      float kv = (float)kb[idx];
      qt[idx] = tobf(qv * expf(run2));
      kt[idx] = tobf(kv * expf(-run2));
      tr[colL][t] = tobf(kv * expf(lc - run2));   // kbar, staged for transpose
    }
    __syncthreads();
#pragma unroll
    for (int i = 0; i < 16; ++i) {
      int row = grp + 4 * i;
      kbarT[((size_t)c * KD + kk0 + row) * 64 + colL] = tr[row][colL];
    }
  } else {
    const int vv0 = tile * 64;
#pragma unroll
    for (int i = 0; i < 16; ++i) {
      int t = grp + 4 * i;
      tr[colL][t] = vb[(size_t)(c * CH + t) * VD + vv0 + colL];
    }
    __syncthreads();
#pragma unroll
    for (int i = 0; i < 16; ++i) {
      int row = grp + 4 * i;
      vT[((size_t)c * VD + vv0 + row) * 64 + colL] = tr[row][colL];
    }
  }
}

// K-split QK^T partials: Ppart[c][ks] = q~ slice @ k~ slice^T (fp32)
__global__ __launch_bounds__(256) void k_qkt(
    const bf16* __restrict__ qt, const bf16* __restrict__ kt,
    float* __restrict__ Ppart)
{
  __shared__ __align__(16) bf16 sA[3 * 64 * 32];
  __shared__ __align__(16) bf16 sB[3 * 64 * 32];
  const int ks = blockIdx.x, c = blockIdx.y;
  const int tid = threadIdx.x, lane = tid & 63;
  const int wr = (tid >> 6) >> 1, wc = (tid >> 6) & 1;
  f32x4 acc[4];
#pragma unroll
  for (int i = 0; i < 4; ++i) acc[i] = fzero();
  gemm_core<64, 64>(qt + (size_t)c * CH * KD + ks * 256, KD, 0,
                    kt + (size_t)c * CH * KD + ks * 256, KD, 0, 256,
                    acc, sA, sB, tid);
  float* dst = Ppart + ((size_t)c * 4 + ks) * 4096;
#pragma unroll
  for (int m = 0; m < 2; ++m)
#pragma unroll
    for (int n = 0; n < 2; ++n) {
      f32x4 v = acc[m * 2 + n];
      int j = wc * 32 + n * 16 + (lane & 15);
#pragma unroll
      for (int r = 0; r < 4; ++r) {
        int t = wr * 32 + m * 16 + (lane >> 4) * 4 + r;
        dst[t * 64 + j] = v[r];
      }
    }
}

// fused U-GEMM + decay scan. Per (vv,kk) 64x64 tile, iterate the group's
// chunks with S held in the MFMA accumulator (fp32):
//   S = d(kk) (.) S ; S += vT_c @ kbarT_c^T (2 MFMA K-steps, C-in = S)
//   write S_c (bf16) to Sstore slot cl.
// grid (16,16) = 256 blocks. 3-buf counted staging, stores-before-stage so
// waitvm<4> counts exactly the next-stage loads.
__global__ __launch_bounds__(256) void k_uscan(
    const bf16* __restrict__ vT, const bf16* __restrict__ kbarT,
    const float* __restrict__ laC, bf16* __restrict__ Sstore,
    float* __restrict__ Sinit, bf16* __restrict__ ScarryB,
    float* __restrict__ dstate, int g)
{
  __shared__ __align__(16) bf16 sA[3 * 4096];   // [buf][ks*2048 + row*32 + kof]
  __shared__ __align__(16) bf16 sB[3 * 4096];
  const int vv0 = blockIdx.x * 64, kk0 = blockIdx.y * 64;
  const int tid = threadIdx.x, lane = tid & 63;
  const int wr = (tid >> 6) >> 1, wc = (tid >> 6) & 1;
  const int srow = tid >> 2, skof = (tid & 3) * 8;

  auto stage = [&](int cl, int buf) {
    const int c = g * CPG + cl;
    const bf16* vP = vT + ((size_t)c * VD + vv0 + srow) * 64 + skof;
    const bf16* kP = kbarT + ((size_t)c * KD + kk0 + srow) * 64 + skof;
    gld16(vP,      sA + buf * 4096 + tid * 8);
    gld16(vP + 32, sA + buf * 4096 + 2048 + tid * 8);
    gld16(kP,      sB + buf * 4096 + tid * 8);
    gld16(kP + 32, sB + buf * 4096 + 2048 + tid * 8);
  };

  // S fragment coordinates (C/D layout): col = col0 + n*16, row = row0 + m*16 + r
  const int col0 = kk0 + wc * 32 + (lane & 15);
  const int row0 = vv0 + wr * 32 + (lane >> 4) * 4;

  f32x4 S[4];
  if (g == 0) {
#pragma unroll
    for (int i = 0; i < 4; ++i) S[i] = fzero();
  } else {
#pragma unroll
    for (int m = 0; m < 2; ++m)
#pragma unroll
      for (int n = 0; n < 2; ++n)
#pragma unroll
        for (int r = 0; r < 4; ++r)
          S[m * 2 + n][r] =
              Sinit[(size_t)(row0 + m * 16 + r) * KD + col0 + n * 16];
  }

  stage(0, 0);
  stage(1, 1);
  float ln0 = laC[(size_t)(g * CPG) * KD + col0];
  float ln1 = laC[(size_t)(g * CPG) * KD + col0 + 16];

  for (int cl = 0; cl < CPG; ++cl) {
    if (cl < CPG - 1) waitvm<4>();
    else              waitvm<0>();
    __builtin_amdgcn_s_barrier();
    __builtin_amdgcn_sched_barrier(0);
    const float d0 = expf(ln0), d1 = expf(ln1);
#pragma unroll
    for (int m = 0; m < 2; ++m)
#pragma unroll
      for (int r = 0; r < 4; ++r) {
        S[m * 2 + 0][r] *= d0;
        S[m * 2 + 1][r] *= d1;
      }
    int buf = cl % 3;
    const bf16* pA = sA + buf * 4096;
    const bf16* pB = sB + buf * 4096;
#pragma unroll
    for (int ks = 0; ks < 2; ++ks) {
      bf16x8 af[2], bfr[2];
#pragma unroll
      for (int m = 0; m < 2; ++m)
        af[m] = *(const bf16x8*)(pA + ks * 2048
                 + (wr * 32 + m * 16 + (lane & 15)) * 32 + (lane >> 4) * 8);
#pragma unroll
      for (int n = 0; n < 2; ++n)
        bfr[n] = *(const bf16x8*)(pB + ks * 2048
                 + (wc * 32 + n * 16 + (lane & 15)) * 32 + (lane >> 4) * 8);
#pragma unroll
      for (int m = 0; m < 2; ++m)
#pragma unroll
        for (int n = 0; n < 2; ++n)
          S[m * 2 + n] = __builtin_amdgcn_mfma_f32_16x16x32_bf16(
              af[m], bfr[n], S[m * 2 + n], 0, 0, 0);
    }
    // write S_c (bf16); these stores precede the next stage() so waitvm<4>
    // at the next iteration leaves only the 4 stage loads outstanding.
    bf16* dst = Sstore + (size_t)cl * KD * VD;
#pragma unroll
    for (int m = 0; m < 2; ++m)
#pragma unroll
      for (int n = 0; n < 2; ++n)
#pragma unroll
        for (int r = 0; r < 4; ++r)
          dst[(size_t)(row0 + m * 16 + r) * KD + col0 + n * 16] =
              tobf(S[m * 2 + n][r]);
    if (cl + 1 < CPG) {
      ln0 = laC[(size_t)(g * CPG + cl + 1) * KD + col0];
      ln1 = laC[(size_t)(g * CPG + cl + 1) * KD + col0 + 16];
    }
    if (cl + 2 < CPG) stage(cl + 2, (cl + 2) % 3);
  }

  if (g < NGROUP - 1) {
    // carry: fp32 (scan continuation) + bf16 (inter2 B-operand)
#pragma unroll
    for (int m = 0; m < 2; ++m)
#pragma unroll
      for (int n = 0; n < 2; ++n)
#pragma unroll
        for (int r = 0; r < 4; ++r) {
          size_t o = (size_t)(row0 + m * 16 + r) * KD + col0 + n * 16;
          Sinit[o] = S[m * 2 + n][r];
          ScarryB[o] = tobf(S[m * 2 + n][r]);
        }
  } else {
    // final state -> dstate [kk][vv] via LDS transpose (reuse sA as fp32)
    float* flds = (float*)sA;                // 64x65 fp32 = 16.6KB < 24KB
    __syncthreads();
#pragma unroll
    for (int m = 0; m < 2; ++m)
#pragma unroll
      for (int n = 0; n < 2; ++n)
#pragma unroll
        for (int r = 0; r < 4; ++r)
          flds[(wr * 32 + m * 16 + (lane >> 4) * 4 + r) * 65
               + wc * 32 + n * 16 + (lane & 15)] = S[m * 2 + n][r];
    __syncthreads();
    const int kkL = tid & 63;
    const int vb0 = (tid >> 6) * 16;
    float* dp = dstate + (size_t)(kk0 + kkL) * VD + vv0 + vb0;
#pragma unroll
    for (int q = 0; q < 4; ++q) {
      float4 o = {flds[(vb0 + q * 4 + 0) * 65 + kkL],
                  flds[(vb0 + q * 4 + 1) * 65 + kkL],
                  flds[(vb0 + q * 4 + 2) * 65 + kkL],
                  flds[(vb0 + q * 4 + 3) * 65 + kkL]};
      *(float4*)(dp + q * 4) = o;
    }
  }
}

// fused: P assemble + inter GEMM (q~_c @ S_{c-1}) + PV (128-col slice)
// -> ob = bf16(intra + inter). grid (8 ntiles, CPG chunks).
__global__ __launch_bounds__(256) void k_inter2(
    const bf16* __restrict__ qt, const float* __restrict__ Ppart,
    const bf16* __restrict__ vT, const bf16* __restrict__ Sstore,
    const bf16* __restrict__ ScarryB, bf16* __restrict__ ob, int g)
{
  __shared__ __align__(16) bf16 sA[3 * 64 * 32];
  __shared__ __align__(16) bf16 sB[3 * 128 * 32];
  __shared__ __align__(16) bf16 Pl[64 * 72];
  __shared__ __align__(16) bf16 sV[128 * 72];
  const int cl = blockIdx.y, c = g * CPG + cl;
  const int n0 = blockIdx.x * 128;
  const int tid = threadIdx.x, lane = tid & 63;
  const int wr = (tid >> 6) >> 1, wc = (tid >> 6) & 1;

  // assemble P = sum of 4 K-partials, causal mask, bf16 into Pl
  {
    const float* base = Ppart + (size_t)c * 4 * 4096;
    const int i0 = tid * 16;
    const int t = tid >> 2;
    const int j0 = (tid & 3) * 16;
#pragma unroll
    for (int e = 0; e < 16; e += 4) {
      float4 s0 = *(const float4*)(base + 0 * 4096 + i0 + e);
      float4 s1 = *(const float4*)(base + 1 * 4096 + i0 + e);
      float4 s2 = *(const float4*)(base + 2 * 4096 + i0 + e);
      float4 s3 = *(const float4*)(base + 3 * 4096 + i0 + e);
      float sx = s0.x + s1.x + s2.x + s3.x;
      float sy = s0.y + s1.y + s2.y + s3.y;
      float sz = s0.z + s1.z + s2.z + s3.z;
      float sw = s0.w + s1.w + s2.w + s3.w;
      int j = j0 + e;
      Pl[t * 72 + j + 0] = (j + 0 <= t) ? tobf(sx) : tobf(0.f);
      Pl[t * 72 + j + 1] = (j + 1 <= t) ? tobf(sy) : tobf(0.f);
      Pl[t * 72 + j + 2] = (j + 2 <= t) ? tobf(sz) : tobf(0.f);
      Pl[t * 72 + j + 3] = (j + 3 <= t) ? tobf(sw) : tobf(0.f);
    }
  }
  __syncthreads();

  f32x4 acc[8];
#pragma unroll
  for (int i = 0; i < 8; ++i) acc[i] = fzero();
  if (c > 0) {
    const bf16* B = (cl == 0) ? ScarryB : Sstore + (size_t)(cl - 1) * KD * VD;
    gemm_core<64, 128>(qt + (size_t)c * CH * KD, KD, 0, B, KD, n0, KD,
                       acc, sA, sB, tid);
  }

  // stage V^T slice rows [n0, n0+128) and add PV into acc
#pragma unroll
  for (int rr = 0; rr < 4; ++rr) {
    int row = rr * 32 + (tid >> 3);
    int j0 = (tid & 7) * 8;
    bf16x8 vv = *(const bf16x8*)(vT + ((size_t)c * VD + n0 + row) * 64 + j0);
    *(bf16x8*)(sV + row * 72 + j0) = vv;
  }
  __syncthreads();
#pragma unroll
  for (int ks = 0; ks < 64; ks += 32) {
    bf16x8 af[2], bfr[4];
#pragma unroll
    for (int m = 0; m < 2; ++m)
      af[m] = *(const bf16x8*)(Pl + (wr * 32 + m * 16 + (lane & 15)) * 72
                               + ks + (lane >> 4) * 8);
#pragma unroll
    for (int n = 0; n < 4; ++n)
      bfr[n] = *(const bf16x8*)(sV + (wc * 64 + n * 16 + (lane & 15)) * 72
                                + ks + (lane >> 4) * 8);
#pragma unroll
    for (int m = 0; m < 2; ++m)
#pragma unroll
      for (int n = 0; n < 4; ++n)
        acc[m * 4 + n] = __builtin_amdgcn_mfma_f32_16x16x32_bf16(
            af[m], bfr[n], acc[m * 4 + n], 0, 0, 0);
  }

#pragma unroll
  for (int m = 0; m < 2; ++m)
#pragma unroll
    for (int n = 0; n < 4; ++n) {
      f32x4 v = acc[m * 4 + n];
      int col = wc * 64 + n * 16 + (lane & 15);
#pragma unroll
      for (int r = 0; r < 4; ++r) {
        int row = wr * 32 + m * 16 + (lane >> 4) * 4 + r;
        ob[((size_t)c * CH + row) * VD + n0 + col] = tobf(v[r]);
      }
    }
}

// y = ob @ Wo^T + bo. BN=64: grid (32, 32) = 1024 blocks, 36KB LDS -> 4/CU.
__global__ __launch_bounds__(256) void k_out(
    const bf16* __restrict__ ob, const bf16* __restrict__ Wob,
    const float* __restrict__ bo, float* __restrict__ out)
{
  __shared__ __align__(16) bf16 sA[3 * 128 * 32];
  __shared__ __align__(16) bf16 sB[3 * 64 * 32];
  const int m0 = blockIdx.x * 128, n0 = blockIdx.y * 64;
  const int tid = threadIdx.x, lane = tid & 63;
  const int wr = (tid >> 6) >> 1, wc = (tid >> 6) & 1;
  f32x4 acc[8];
#pragma unroll
  for (int i = 0; i < 8; ++i) acc[i] = fzero();
  gemm_core<128, 64>(ob, VD, m0, Wob, VD, n0, VD, acc, sA, sB, tid);
#pragma unroll
  for (int m = 0; m < 4; ++m)
#pragma unroll
    for (int n = 0; n < 2; ++n) {
      f32x4 v = acc[m * 2 + n];
      int col = n0 + wc * 32 + n * 16 + (lane & 15);
      float b = bo[col];
#pragma unroll
      for (int r = 0; r < 4; ++r) {
        int row = m0 + wr * 64 + m * 16 + (lane >> 4) * 4 + r;
        out[(size_t)row * OD + col] = v[r] + b;
      }
    }
}

// ---------------------------------------------------------------------------
extern "C" void kernel_launch(void* const* d_in, const int* in_sizes, int n_in,
                              void* d_out, int out_size, void* d_ws, size_t ws_size,
                              hipStream_t stream)
{
  const float* hs = (const float*)d_in[0];
  const float* Wq = (const float*)d_in[1];
  const float* bq = (const float*)d_in[2];
  const float* Wk = (const float*)d_in[3];
  const float* bk = (const float*)d_in[4];
  const float* Wv = (const float*)d_in[5];
  const float* bv = (const float*)d_in[6];
  const float* Wg = (const float*)d_in[7];
  const float* bg = (const float*)d_in[8];
  const float* Wo = (const float*)d_in[9];
  const float* bo = (const float*)d_in[10];
  float* out = (float*)d_out;
  float* dstate = out + (size_t)T_ * OD;

  char* p = (char*)d_ws;
  auto alloc = [&](size_t b) -> char* {
    char* r = p; p += (b + 255) & ~(size_t)255; return r;
  };
  bf16* hsb    = (bf16*)alloc((size_t)T_ * H_ * 2);
  bf16* Wqb    = (bf16*)alloc((size_t)KD * H_ * 2);
  bf16* Wkb    = (bf16*)alloc((size_t)KD * H_ * 2);
  bf16* Wgb    = (bf16*)alloc((size_t)KD * H_ * 2);
  bf16* Wvb    = (bf16*)alloc((size_t)VD * H_ * 2);
  bf16* Wob    = (bf16*)alloc((size_t)OD * VD * 2);
  bf16* qb     = (bf16*)alloc((size_t)T_ * KD * 2);
  bf16* kb     = (bf16*)alloc((size_t)T_ * KD * 2);
  float* la    = (float*)alloc((size_t)T_ * KD * 4);
  bf16* vb     = (bf16*)alloc((size_t)T_ * VD * 2);
  bf16* qt     = (bf16*)alloc((size_t)T_ * KD * 2);
  bf16* kt     = (bf16*)alloc((size_t)T_ * KD * 2);
  bf16* kbarT  = (bf16*)alloc((size_t)T_ * KD * 2);
  bf16* vT     = (bf16*)alloc((size_t)T_ * VD * 2);
  bf16* ob     = (bf16*)alloc((size_t)T_ * VD * 2);
  float* Sinit = (float*)alloc((size_t)KD * VD * 4);
  bf16* ScarryB= (bf16*)alloc((size_t)KD * VD * 2);
  bf16* Sstore = (bf16*)alloc((size_t)CPG * KD * VD * 2);   // 64 MB
  float* laC   = (float*)alloc((size_t)NCHUNK * KD * 4);
  float* Ppart = (float*)alloc((size_t)NCHUNK * 4 * 4096 * 4);
  if ((size_t)(p - (char*)d_ws) > ws_size) return;

  // pbuf (proj partials, 64MB bf16) reuses Sstore: free until first k_uscan.
  bf16* pbuf = Sstore;

  k_cvt6<<<(int)((CVT_TOT / 4 + 255) / 256), 256, 0, stream>>>(
      hs, Wq, Wk, Wg, Wv, Wo, hsb, Wqb, Wkb, Wgb, Wvb, Wob);

  k_projA<<<dim3(T_ / 128, 32, 2), 256, 0, stream>>>(
      hsb, Wqb, Wkb, Wgb, Wvb, pbuf);
  k_projB<<<(int)((size_t)T_ * 4096 / 8 / 256), 256, 0, stream>>>(
      pbuf, bq, bk, bg, bv, qb, kb, la, vb);

  k_transform<<<dim3(16, NCHUNK, 2), 256, 0, stream>>>(
      qb, kb, la, vb, qt, kt, kbarT, vT, laC);

  k_qkt<<<dim3(4, NCHUNK), 256, 0, stream>>>(qt, kt, Ppart);

  for (int g = 0; g < NGROUP; ++g) {
    k_uscan<<<dim3(16, 16), 256, 0, stream>>>(
        vT, kbarT, laC, Sstore, Sinit, ScarryB, dstate, g);
    k_inter2<<<dim3(8, CPG), 256, 0, stream>>>(
        qt, Ppart, vT, Sstore, ScarryB, ob, g);
  }

  k_out<<<dim3(T_ / 128, OD / 64), 256, 0, stream>>>(ob, Wob, bo, out);
}